// Round 12
// baseline (111.289 us; speedup 1.0000x reference)
//
#include <hip/hip_runtime.h>
#include <hip/hip_bf16.h>

typedef __attribute__((ext_vector_type(8))) short bf16x8;
typedef __attribute__((ext_vector_type(16))) float f32x16;
typedef __attribute__((ext_vector_type(4))) unsigned short u16x4;

#define TT 128
#define DD 256
#define NJ 8              // j's per block
#define VID0 0            // video K-half panels (32 KiB each, persistent)
#define VID1 32768
#define WIF0 65536        // wifi half-panel stream buffers (32 KiB each)
#define WIF1 98304
#define PARTOFF 131072    // 2 x 6144 B partial buffers
#define K2L 2.8853900817779268f   // 2*log2(e): exp(2x) = exp2(x*K2L)

__device__ __forceinline__ unsigned short f2bf(float f) {
  unsigned int x = __float_as_uint(f);
  x += 0x7fffu + ((x >> 16) & 1u);          // round-to-nearest-even
  return (unsigned short)(x >> 16);
}

__device__ __forceinline__ bf16x8 pack8(float4 lo, float4 hi) {
  bf16x8 v;
  v[0] = (short)f2bf(lo.x); v[1] = (short)f2bf(lo.y);
  v[2] = (short)f2bf(lo.z); v[3] = (short)f2bf(lo.w);
  v[4] = (short)f2bf(hi.x); v[5] = (short)f2bf(hi.y);
  v[6] = (short)f2bf(hi.z); v[7] = (short)f2bf(hi.w);
  return v;
}

// One-shot f32 -> bf16 preconversion of both feature tensors.
__global__ __launch_bounds__(256) void conv_kernel(
    const float* __restrict__ v, const float* __restrict__ w,
    unsigned short* __restrict__ vb, unsigned short* __restrict__ wb) {
  const int idx = blockIdx.x * 256 + threadIdx.x;   // float4 units
  float4 a = reinterpret_cast<const float4*>(v)[idx];
  float4 b = reinterpret_cast<const float4*>(w)[idx];
  u16x4 pa, pb;
  pa[0] = f2bf(a.x); pa[1] = f2bf(a.y); pa[2] = f2bf(a.z); pa[3] = f2bf(a.w);
  pb[0] = f2bf(b.x); pb[1] = f2bf(b.y); pb[2] = f2bf(b.z); pb[3] = f2bf(b.w);
  reinterpret_cast<u16x4*>(vb)[idx] = pa;
  reinterpret_cast<u16x4*>(wb)[idx] = pb;
}

// Half-panel layout (PROVEN 0-conflict, R9-R11): 128 rows x 256 B; row r at
// r*256, 16-byte slot s at ((s ^ (r & 15)) << 4).
#define FR(BASE, ROW, KSLOT)                                                  \
  (*(const bf16x8*)(lds + (BASE) + (ROW) * 256 +                              \
                    ((((KSLOT)) ^ ((ROW) & 15)) << 4)))

// Strip kernel: one workgroup (512 thr, 8 waves) per (i, jg); processes
// j = jg*NJ .. +NJ-1.  Video[i] staged ONCE into persistent LDS (2 K-half
// panels); wifi[j] half-panels stream through 2 buffers (R9's pipeline:
// compute h0 | stage h1 -> buf1 | compute h1 | stage next h0 -> buf0).
// Dual-orientation 32x32x16 MFMA, wave tile 64x64 (o=wid>>2, mg, cg).
// Per-j epilogue: reg-local max/exp + shfl32 + LDS merge (dbuf partials);
// waves 0/1 frame-pool j-1 overlapped with j's compute, atomicAdd to dense.
template <bool PRE>
__global__ __launch_bounds__(512, 2) void pair_kernel(
    const float* __restrict__ videof, const float* __restrict__ wifif,
    const unsigned short* __restrict__ videob,
    const unsigned short* __restrict__ wifib,
    float* __restrict__ dense) {
  __shared__ __align__(16) char lds[143360];
  const int tid = threadIdx.x;
  const int bid = blockIdx.x;
  const int i  = bid >> 3, jg = bid & 7;
  const int wid = tid >> 6, l = tid & 63;
  const int l31 = l & 31;
  const int khalf = l >> 5;

  const int o  = wid >> 2;          // orientation: 0 S=video x wifi^T, 1 St
  const int mg = wid & 1;           // row half of X
  const int cg = (wid >> 1) & 1;    // col half of Y

  if (tid < NJ) dense[i * 64 + jg * NJ + tid] = 0.0f;   // block-owned entries

  const char* vsrc  = (const char*)videob + (size_t)i * (TT * DD * 2);
  const char* wsrc0 = (const char*)wifib + (size_t)(jg * NJ) * (TT * DD * 2);
  const float* vsrcf  = videof + (size_t)i * (TT * DD);
  const float* wsrcf0 = wifif + (size_t)(jg * NJ) * (TT * DD);

  // staging lane indices (PRE): chunk = 4 rows x 256 B (1 KiB); lane ->
  // row c*4 + (l>>4), slot l&15; source slot inverse-swizzled (G21).
  const int crow  = l >> 4;
  const int cslot = l & 15;
  // fallback (non-PRE)
  const int frow = tid >> 2, fq = tid & 3;

  const int xr0 = mg * 64 + l31, xr1 = mg * 64 + 32 + l31;
  const int yc0 = cg * 64 + l31, yc1 = cg * 64 + 32 + l31;

  // ---- stage video (both K-halves, persistent) ----
#define STAGE_VID_PRE_()                                                      \
  do {                                                                        \
    _Pragma("unroll") for (int k_ = 0; k_ < 8; ++k_) {                        \
      const int q_ = wid * 8 + k_;          /* 0..63 */                       \
      const int h_ = q_ >> 5;                                                 \
      const int c_ = q_ & 31;                                                 \
      const int r_ = c_ * 4 + crow;                                           \
      const char* s_ = vsrc + r_ * 512 + h_ * 256 +                           \
                       ((cslot ^ (r_ & 15)) << 4);                            \
      char* d_ = lds + h_ * 32768 + c_ * 1024;                                \
      __builtin_amdgcn_global_load_lds((const void*)s_, (void*)d_, 16, 0, 0); \
    }                                                                         \
  } while (0)

#define STAGE_VID_REG_()                                                      \
  do {                                                                        \
    _Pragma("unroll") for (int h_ = 0; h_ < 2; ++h_)                          \
      _Pragma("unroll") for (int s_ = 0; s_ < 4; ++s_) {                      \
        const int slot_ = fq * 4 + s_;                                        \
        const float* p_ = vsrcf + frow * DD + h_ * 128 + slot_ * 8;           \
        float4 x0_ = *(const float4*)(p_);                                    \
        float4 x1_ = *(const float4*)(p_ + 4);                                \
        *(bf16x8*)(lds + h_ * 32768 + frow * 256 +                            \
                   ((slot_ ^ (frow & 15)) << 4)) = pack8(x0_, x1_);           \
      }                                                                       \
  } while (0)

  // ---- stage one wifi K-half of panel jj into WIF buffer ----
#define STAGE_WIF_PRE_(JJ, KH, BUF)                                           \
  do {                                                                        \
    const char* ws_ = wsrc0 + (size_t)(JJ) * (TT * DD * 2);                   \
    _Pragma("unroll") for (int k_ = 0; k_ < 4; ++k_) {                        \
      const int c_ = wid * 4 + k_;          /* 0..31 */                       \
      const int r_ = c_ * 4 + crow;                                           \
      const char* s_ = ws_ + r_ * 512 + (KH) * 256 +                          \
                       ((cslot ^ (r_ & 15)) << 4);                            \
      char* d_ = lds + WIF0 + (BUF) * 32768 + c_ * 1024;                      \
      __builtin_amdgcn_global_load_lds((const void*)s_, (void*)d_, 16, 0, 0); \
    }                                                                         \
  } while (0)

#define STAGE_WIF_REG_(JJ, KH, BUF)                                           \
  do {                                                                        \
    const float* ws_ = wsrcf0 + (size_t)(JJ) * (TT * DD);                     \
    _Pragma("unroll") for (int s_ = 0; s_ < 4; ++s_) {                        \
      const int slot_ = fq * 4 + s_;                                          \
      const float* p_ = ws_ + frow * DD + (KH) * 128 + slot_ * 8;             \
      float4 x0_ = *(const float4*)(p_);                                      \
      float4 x1_ = *(const float4*)(p_ + 4);                                  \
      *(bf16x8*)(lds + WIF0 + (BUF) * 32768 + frow * 256 +                    \
                 ((slot_ ^ (frow & 15)) << 4)) = pack8(x0_, x1_);             \
    }                                                                         \
  } while (0)

  f32x16 acc[2][2];

#define COMPUTE_(VB, WB)                                                      \
  do {                                                                        \
    const int xb_ = o ? (WB) : (VB);                                          \
    const int yb_ = o ? (VB) : (WB);                                          \
    _Pragma("unroll") for (int ksl = 0; ksl < 8; ++ksl) {                     \
      const int kslot_ = 2 * ksl + khalf;                                     \
      bf16x8 x0_ = FR(xb_, xr0, kslot_);                                      \
      bf16x8 x1_ = FR(xb_, xr1, kslot_);                                      \
      bf16x8 y0_ = FR(yb_, yc0, kslot_);                                      \
      bf16x8 y1_ = FR(yb_, yc1, kslot_);                                      \
      acc[0][0] = __builtin_amdgcn_mfma_f32_32x32x16_bf16(x0_, y0_, acc[0][0], 0, 0, 0); \
      acc[0][1] = __builtin_amdgcn_mfma_f32_32x32x16_bf16(x0_, y1_, acc[0][1], 0, 0, 0); \
      acc[1][0] = __builtin_amdgcn_mfma_f32_32x32x16_bf16(x1_, y0_, acc[1][0], 0, 0, 0); \
      acc[1][1] = __builtin_amdgcn_mfma_f32_32x32x16_bf16(x1_, y1_, acc[1][1], 0, 0, 0); \
    }                                                                         \
  } while (0)

#define EPILOGUE(JJ)                                                          \
  do {                                                                        \
    float* P_ = (float*)(lds + PARTOFF + ((JJ) & 1) * 6144);                  \
    _Pragma("unroll") for (int t = 0; t < 2; ++t) {                           \
      float mx = acc[0][t][0];                                                \
      _Pragma("unroll") for (int r = 1; r < 16; ++r) mx = fmaxf(mx, acc[0][t][r]); \
      _Pragma("unroll") for (int r = 0; r < 16; ++r) mx = fmaxf(mx, acc[1][t][r]); \
      const float mxk = mx * K2L;                                             \
      float se = 0.f, sv = 0.f;                                               \
      _Pragma("unroll") for (int mi = 0; mi < 2; ++mi)                        \
        _Pragma("unroll") for (int r = 0; r < 16; ++r) {                      \
          const float v = acc[mi][t][r];                                      \
          const float e = exp2f(fmaf(v, K2L, -mxk));                          \
          se += e; sv = fmaf(e, v, sv);                                       \
        }                                                                     \
      const float om = __shfl_xor(mx, 32);                                    \
      const float os = __shfl_xor(se, 32);                                    \
      const float ov = __shfl_xor(sv, 32);                                    \
      const float M = fmaxf(mx, om);                                          \
      const float f1 = exp2f((mx - M) * K2L);                                 \
      const float f2 = exp2f((om - M) * K2L);                                 \
      se = fmaf(se, f1, os * f2);                                             \
      sv = fmaf(sv, f1, ov * f2);                                             \
      if (l < 32) {                                                           \
        const int idx_ = o * 256 + mg * 128 + cg * 64 + t * 32 + l;           \
        P_[idx_] = M; P_[512 + idx_] = se; P_[1024 + idx_] = sv;              \
      }                                                                       \
    }                                                                         \
  } while (0)

#define REDUCE(JJ)                                                            \
  do {                                                                        \
    const float* P_ = (const float*)(lds + PARTOFF + ((JJ) & 1) * 6144);      \
    const int oo_ = (wid == 0) ? 1 : 0;                                       \
    float a0_, a1_;                                                           \
    {                                                                         \
      const int c_ = oo_ * 256 + l;                                           \
      const float m0 = P_[c_], m1 = P_[c_ + 128];                             \
      const float M = fmaxf(m0, m1);                                          \
      const float f0 = exp2f((m0 - M) * K2L);                                 \
      const float f1 = exp2f((m1 - M) * K2L);                                 \
      a0_ = fmaf(P_[1024 + c_], f0, P_[1024 + c_ + 128] * f1) /               \
            fmaf(P_[512 + c_], f0, P_[512 + c_ + 128] * f1);                  \
    }                                                                         \
    {                                                                         \
      const int c_ = oo_ * 256 + 64 + l;                                      \
      const float m0 = P_[c_], m1 = P_[c_ + 128];                             \
      const float M = fmaxf(m0, m1);                                          \
      const float f0 = exp2f((m0 - M) * K2L);                                 \
      const float f1 = exp2f((m1 - M) * K2L);                                 \
      a1_ = fmaf(P_[1024 + c_], f0, P_[1024 + c_ + 128] * f1) /               \
            fmaf(P_[512 + c_], f0, P_[512 + c_ + 128] * f1);                  \
    }                                                                         \
    float mx_ = fmaxf(a0_, a1_);                                              \
    _Pragma("unroll") for (int s_ = 1; s_ < 64; s_ <<= 1)                     \
      mx_ = fmaxf(mx_, __shfl_xor(mx_, s_));                                  \
    const float e0_ = exp2f((a0_ - mx_) * K2L);                               \
    const float e1_ = exp2f((a1_ - mx_) * K2L);                               \
    float se_ = e0_ + e1_, sev_ = fmaf(e0_, a0_, e1_ * a1_);                  \
    _Pragma("unroll") for (int s_ = 1; s_ < 64; s_ <<= 1) {                   \
      se_ += __shfl_xor(se_, s_); sev_ += __shfl_xor(sev_, s_);               \
    }                                                                         \
    if (l == 0)                                                               \
      atomicAdd(dense + i * 64 + jg * NJ + (JJ), 0.5f * (sev_ / se_));        \
  } while (0)

  // ---- prologue: video (both halves) + wifi(0,h0) -> buf0 ----
  if constexpr (PRE) { STAGE_VID_PRE_(); STAGE_WIF_PRE_(0, 0, 0); }
  else               { STAGE_VID_REG_(); STAGE_WIF_REG_(0, 0, 0); }
  __syncthreads();

  // ---- j loop (R9's proven pipeline shape) ----
  for (int jj = 0; jj < NJ; ++jj) {
    // h0: stage (jj,h1)->buf1, compute buf0 against video h0
    if constexpr (PRE) STAGE_WIF_PRE_(jj, 1, 1); else STAGE_WIF_REG_(jj, 1, 1);
#pragma unroll
    for (int mi = 0; mi < 2; ++mi)
#pragma unroll
      for (int t = 0; t < 2; ++t)
#pragma unroll
        for (int r = 0; r < 16; ++r) acc[mi][t][r] = 0.f;
    COMPUTE_(VID0, WIF0);
    __syncthreads();                 // buf1 ready; buf0 consumed
    // h1: stage (jj+1,h0)->buf0, compute buf1 against video h1
    if (jj < NJ - 1) {
      if constexpr (PRE) STAGE_WIF_PRE_(jj + 1, 0, 0);
      else STAGE_WIF_REG_(jj + 1, 0, 0);
    }
    COMPUTE_(VID1, WIF1);
    EPILOGUE(jj);
    __syncthreads();                 // buf0 ready; partials visible
    if (wid < 2) REDUCE(jj);         // overlaps next jj's compute
  }
}

// Label-smoothed symmetric CE over the 64x64 dense-similarity matrix. f32 out.
__global__ __launch_bounds__(64) void loss_kernel(
    const float* __restrict__ dense, const float* __restrict__ scalep,
    float* __restrict__ out) {
  const int i = threadIdx.x;
  const float sc = fminf(scalep[0], 40.0f);
  float mxr = -3.4e38f, mxc = -3.4e38f;
  for (int j = 0; j < 64; ++j) {
    mxr = fmaxf(mxr, sc * dense[i * 64 + j]);
    mxc = fmaxf(mxc, sc * dense[j * 64 + i]);
  }
  float ser = 0.f, sec = 0.f, slr = 0.f, slc = 0.f;
  for (int j = 0; j < 64; ++j) {
    float zr = sc * dense[i * 64 + j];
    float zc = sc * dense[j * 64 + i];
    ser += __expf(zr - mxr); sec += __expf(zc - mxc);
    slr += zr;               slc += zc;
  }
  const float lser = mxr + logf(ser);
  const float lsec = mxc + logf(sec);
  const float zd = sc * dense[i * 65];
  float lv = lser - 0.9f * zd - 0.1f * (slr * (1.0f / 64.0f));
  float lw = lsec - 0.9f * zd - 0.1f * (slc * (1.0f / 64.0f));
  float t = 0.5f * (lv + lw);
#pragma unroll
  for (int s = 1; s < 64; s <<= 1) t += __shfl_xor(t, s);
  if (i == 0) out[0] = t * (1.0f / 64.0f);
}

extern "C" void kernel_launch(void* const* d_in, const int* in_sizes, int n_in,
                              void* d_out, int out_size, void* d_ws, size_t ws_size,
                              hipStream_t stream) {
  (void)in_sizes; (void)n_in; (void)out_size;
  const float* video = (const float*)d_in[0];
  const float* wifi  = (const float*)d_in[1];
  const float* scale = (const float*)d_in[2];
  float* dense = (float*)d_ws;                                   // 16 KiB
  unsigned short* vb = (unsigned short*)((char*)d_ws + 16384);   // 4 MiB
  unsigned short* wb = vb + 64 * TT * DD;                        // 4 MiB

  const bool pre = ws_size >= (size_t)16384 + 2u * 64 * TT * DD * 2;
  if (pre) {
    hipLaunchKernelGGL(conv_kernel, dim3(2048), dim3(256), 0, stream,
                       video, wifi, vb, wb);
    hipLaunchKernelGGL((pair_kernel<true>), dim3(512), dim3(512), 0, stream,
                       video, wifi, vb, wb, dense);
  } else {
    hipLaunchKernelGGL((pair_kernel<false>), dim3(512), dim3(512), 0, stream,
                       video, wifi, vb, wb, dense);
  }
  hipLaunchKernelGGL(loss_kernel, dim3(1), dim3(64), 0, stream,
                     dense, scale, (float*)d_out);
}

// Round 13
// 103.412 us; speedup vs baseline: 1.0762x; 1.0762x over previous
//
#include <hip/hip_runtime.h>
#include <hip/hip_bf16.h>

typedef __attribute__((ext_vector_type(8))) short bf16x8;
typedef __attribute__((ext_vector_type(16))) float f32x16;
typedef __attribute__((ext_vector_type(4))) unsigned short u16x4;

#define TT 128
#define DD 256
#define BK 64
#define BPAN 16384       // B panel offset (panels 16 KiB each, single-buffered)
#define PART 32768       // partials offset
#define K2L 2.8853900817779268f   // 2*log2(e): exp(2x) = exp2(x*K2L)

__device__ __forceinline__ unsigned short f2bf(float f) {
  unsigned int x = __float_as_uint(f);
  x += 0x7fffu + ((x >> 16) & 1u);          // round-to-nearest-even
  return (unsigned short)(x >> 16);
}

__device__ __forceinline__ bf16x8 pack8(float4 lo, float4 hi) {
  bf16x8 v;
  v[0] = (short)f2bf(lo.x); v[1] = (short)f2bf(lo.y);
  v[2] = (short)f2bf(lo.z); v[3] = (short)f2bf(lo.w);
  v[4] = (short)f2bf(hi.x); v[5] = (short)f2bf(hi.y);
  v[6] = (short)f2bf(hi.z); v[7] = (short)f2bf(hi.w);
  return v;
}

// One-shot f32 -> bf16 preconversion of both feature tensors.
__global__ __launch_bounds__(256) void conv_kernel(
    const float* __restrict__ v, const float* __restrict__ w,
    unsigned short* __restrict__ vb, unsigned short* __restrict__ wb) {
  const int idx = blockIdx.x * 256 + threadIdx.x;   // float4 units
  float4 a = reinterpret_cast<const float4*>(v)[idx];
  float4 b = reinterpret_cast<const float4*>(w)[idx];
  u16x4 pa, pb;
  pa[0] = f2bf(a.x); pa[1] = f2bf(a.y); pa[2] = f2bf(a.z); pa[3] = f2bf(a.w);
  pb[0] = f2bf(b.x); pb[1] = f2bf(b.y); pb[2] = f2bf(b.z); pb[3] = f2bf(b.w);
  reinterpret_cast<u16x4*>(vb)[idx] = pa;
  reinterpret_cast<u16x4*>(wb)[idx] = pb;
}

// One workgroup (512 thr, 8 waves) per (i,j).  Dual-orientation 32x32x16
// MFMA GEMM, wave tile 64x64.  SINGLE-buffered 16 KiB panels, strict
// stage | barrier | compute | barrier phases.  38.25 KiB LDS ->
// 4 blocks/CU (= 32 waves, full occupancy); each block's stage-drain and
// barrier stalls are hidden by the other 3 resident blocks (TLP), which
// the R4-R12 occupancy gradient shows is the only lever that moved dur.
// __launch_bounds__(512, 4): R5 measured VGPR 56, no spill, with this
// bound; (512,8) capped VGPR at 32 and spilled the accumulator (R8).
template <bool PRE>
__global__ __launch_bounds__(512, 4) void pair_kernel(
    const float* __restrict__ videof, const float* __restrict__ wifif,
    const unsigned short* __restrict__ videob,
    const unsigned short* __restrict__ wifib,
    float* __restrict__ dense) {
  __shared__ __align__(16) char lds[39168];
  const int tid = threadIdx.x;
  const int bid = blockIdx.x;
  const int bi = bid >> 6, bj = bid & 63;
  const int wid = tid >> 6, l = tid & 63;
  const int l31 = l & 31;

  const int o  = wid >> 2;          // orientation
  const int mg = wid & 1;           // 64-row half of X
  const int cg = (wid >> 1) & 1;    // 64-col half of Y

  // ---- staging constants ----
  const char* vsrc = (const char*)videob + (size_t)bi * (TT * DD * 2);
  const char* wsrc = (const char*)wifib  + (size_t)bj * (TT * DD * 2);
  const int grow8 = l >> 3;                       // row within 8-row chunk
  const int gcb   = ((l & 7) ^ grow8) << 4;       // inverse-swizzled src byte
  // non-PRE fallback
  const int srow = tid >> 2;
  const int scb  = (tid & 3) * 32;
  const int sswz = (srow & 7) << 4;
  const int sb0  = srow * 128 + ((scb) ^ sswz);
  const int sb1  = srow * 128 + ((scb + 16) ^ sswz);

  f32x16 acc[2][2];
#pragma unroll
  for (int mi = 0; mi < 2; ++mi)
#pragma unroll
    for (int t = 0; t < 2; ++t)
#pragma unroll
      for (int r = 0; r < 16; ++r) acc[mi][t][r] = 0.f;

  const int apan = o ? BPAN : 0;    // X panel (wifi when o=1)
  const int bpan = o ? 0 : BPAN;    // Y panel
  const int xr    = (l31 & 7) << 4; // read-side swizzle
  const int khalf = (l >> 5) * 16;
  const int xbase = (mg * 64 + l31) * 128;
  const int ybase = (cg * 64 + l31) * 128;

#define STAGE_PRE(KP)                                                         \
  do {                                                                        \
    _Pragma("unroll") for (int k_ = 0; k_ < 4; ++k_) {                        \
      const int q_ = wid * 4 + k_;                                            \
      const int c_ = q_ & 15;                                                 \
      const char* s_ = ((q_ < 16) ? vsrc : wsrc) + (c_ * 8 + grow8) * 512 +   \
                       (KP) * 128 + gcb;                                      \
      char* d_ = lds + ((q_ < 16) ? 0 : BPAN) + c_ * 1024;                    \
      __builtin_amdgcn_global_load_lds((const void*)s_, (void*)d_, 16, 0, 0); \
    }                                                                         \
  } while (0)

#define STAGE_REG(KP)                                                         \
  do {                                                                        \
    const float* pa_ = videof + (size_t)bi * (TT * DD) + srow * DD +          \
                       (KP) * BK + (tid & 3) * 16;                            \
    const float* pb_ = wifif + (size_t)bj * (TT * DD) + srow * DD +           \
                       (KP) * BK + (tid & 3) * 16;                            \
    float4 a0_ = *(const float4*)(pa_);                                       \
    float4 a1_ = *(const float4*)(pa_ + 4);                                   \
    float4 a2_ = *(const float4*)(pa_ + 8);                                   \
    float4 a3_ = *(const float4*)(pa_ + 12);                                  \
    float4 b0_ = *(const float4*)(pb_);                                       \
    float4 b1_ = *(const float4*)(pb_ + 4);                                   \
    float4 b2_ = *(const float4*)(pb_ + 8);                                   \
    float4 b3_ = *(const float4*)(pb_ + 12);                                  \
    *(bf16x8*)(lds + sb0)        = pack8(a0_, a1_);                           \
    *(bf16x8*)(lds + sb1)        = pack8(a2_, a3_);                           \
    *(bf16x8*)(lds + BPAN + sb0) = pack8(b0_, b1_);                           \
    *(bf16x8*)(lds + BPAN + sb1) = pack8(b2_, b3_);                           \
  } while (0)

  if constexpr (PRE) STAGE_PRE(0); else STAGE_REG(0);
  __syncthreads();                      // drains gload_lds writes

  for (int kp = 0; kp < 4; ++kp) {
    const char* xb = lds + apan + xbase;
    const char* yb = lds + bpan + ybase;
#pragma unroll
    for (int ks = 0; ks < 4; ++ks) {
      const int off = (ks * 32 + khalf) ^ xr;
      bf16x8 ax0 = *(const bf16x8*)(xb + off);
      bf16x8 ax1 = *(const bf16x8*)(xb + 4096 + off);
      bf16x8 by0 = *(const bf16x8*)(yb + off);
      bf16x8 by1 = *(const bf16x8*)(yb + 4096 + off);
      acc[0][0] = __builtin_amdgcn_mfma_f32_32x32x16_bf16(ax0, by0, acc[0][0], 0, 0, 0);
      acc[0][1] = __builtin_amdgcn_mfma_f32_32x32x16_bf16(ax0, by1, acc[0][1], 0, 0, 0);
      acc[1][0] = __builtin_amdgcn_mfma_f32_32x32x16_bf16(ax1, by0, acc[1][0], 0, 0, 0);
      acc[1][1] = __builtin_amdgcn_mfma_f32_32x32x16_bf16(ax1, by1, acc[1][1], 0, 0, 0);
    }
    __syncthreads();                    // all reads of this panel done
    if (kp < 3) {
      if constexpr (PRE) STAGE_PRE(kp + 1); else STAGE_REG(kp + 1);
      __syncthreads();                  // writes landed
    }
  }

  // ---- pooling partials: PM/PS/PV [o][mg][128] f32 ----
  float* PM = (float*)(lds + PART);
  float* PS = PM + 512;
  float* PV = PM + 1024;
  float* Gb = PM + 1536;

  // per-column: local max + exp-sums over 32 rows, then softmax-merge with
  // lane^32 (the other interleaved 32 rows of this wave's 64).
#pragma unroll
  for (int t = 0; t < 2; ++t) {
    float mx = acc[0][t][0];
#pragma unroll
    for (int r = 1; r < 16; ++r) mx = fmaxf(mx, acc[0][t][r]);
#pragma unroll
    for (int r = 0; r < 16; ++r) mx = fmaxf(mx, acc[1][t][r]);
    const float mxk = mx * K2L;
    float se = 0.f, sv = 0.f;
#pragma unroll
    for (int mi = 0; mi < 2; ++mi)
#pragma unroll
      for (int r = 0; r < 16; ++r) {
        const float v = acc[mi][t][r];
        const float e = exp2f(fmaf(v, K2L, -mxk));
        se += e;
        sv = fmaf(e, v, sv);
      }
    const float om = __shfl_xor(mx, 32);
    const float os = __shfl_xor(se, 32);
    const float ov = __shfl_xor(sv, 32);
    const float M  = fmaxf(mx, om);
    const float f1 = exp2f((mx - M) * K2L);
    const float f2 = exp2f((om - M) * K2L);
    se = fmaf(se, f1, os * f2);
    sv = fmaf(sv, f1, ov * f2);
    if (l < 32) {
      const int idx = o * 256 + mg * 128 + cg * 64 + t * 32 + l;
      PM[idx] = M; PS[idx] = se; PV[idx] = sv;
    }
  }
  __syncthreads();

  // merge the two 64-row halves per column -> soft_sim value (into PM row 0)
  if (tid < 256) {
    const int o2 = tid >> 7, c = tid & 127;
    const int i0 = o2 * 256 + c, i1 = i0 + 128;
    const float m0 = PM[i0], m1 = PM[i1];
    const float M  = fmaxf(m0, m1);
    const float f0 = exp2f((m0 - M) * K2L);
    const float f1 = exp2f((m1 - M) * K2L);
    const float s  = fmaf(PS[i0], f0, PS[i1] * f1);
    const float v  = fmaf(PV[i0], f0, PV[i1] * f1);
    PM[i0] = v / s;
  }
  __syncthreads();

  // frame-level softmax pooling -> scalars
  // wave 0: v2w (cols = video frames -> o=1 partials); wave 1: w2v (o=0)
  if (wid < 2) {
    const float* RS = PM + (wid == 0 ? 256 : 0);
    float a0 = RS[l], a1 = RS[64 + l];
    float mx = fmaxf(a0, a1);
#pragma unroll
    for (int s = 1; s < 64; s <<= 1) mx = fmaxf(mx, __shfl_xor(mx, s));
    float e0 = exp2f((a0 - mx) * K2L), e1 = exp2f((a1 - mx) * K2L);
    float se = e0 + e1, sev = fmaf(e0, a0, e1 * a1);
#pragma unroll
    for (int s = 1; s < 64; s <<= 1) { se += __shfl_xor(se, s); sev += __shfl_xor(sev, s); }
    if (l == 0) Gb[wid] = sev / se;
  }
  __syncthreads();
  if (tid == 0) dense[bid] = 0.5f * (Gb[0] + Gb[1]);
}

// Label-smoothed symmetric CE over the 64x64 dense-similarity matrix. f32 out.
__global__ __launch_bounds__(64) void loss_kernel(
    const float* __restrict__ dense, const float* __restrict__ scalep,
    float* __restrict__ out) {
  const int i = threadIdx.x;
  const float sc = fminf(scalep[0], 40.0f);
  float mxr = -3.4e38f, mxc = -3.4e38f;
  for (int j = 0; j < 64; ++j) {
    mxr = fmaxf(mxr, sc * dense[i * 64 + j]);
    mxc = fmaxf(mxc, sc * dense[j * 64 + i]);
  }
  float ser = 0.f, sec = 0.f, slr = 0.f, slc = 0.f;
  for (int j = 0; j < 64; ++j) {
    float zr = sc * dense[i * 64 + j];
    float zc = sc * dense[j * 64 + i];
    ser += __expf(zr - mxr); sec += __expf(zc - mxc);
    slr += zr;               slc += zc;
  }
  const float lser = mxr + logf(ser);
  const float lsec = mxc + logf(sec);
  const float zd = sc * dense[i * 65];
  float lv = lser - 0.9f * zd - 0.1f * (slr * (1.0f / 64.0f));
  float lw = lsec - 0.9f * zd - 0.1f * (slc * (1.0f / 64.0f));
  float t = 0.5f * (lv + lw);
#pragma unroll
  for (int s = 1; s < 64; s <<= 1) t += __shfl_xor(t, s);
  if (i == 0) out[0] = t * (1.0f / 64.0f);
}

extern "C" void kernel_launch(void* const* d_in, const int* in_sizes, int n_in,
                              void* d_out, int out_size, void* d_ws, size_t ws_size,
                              hipStream_t stream) {
  (void)in_sizes; (void)n_in; (void)out_size;
  const float* video = (const float*)d_in[0];
  const float* wifi  = (const float*)d_in[1];
  const float* scale = (const float*)d_in[2];
  float* dense = (float*)d_ws;                                   // 16 KiB
  unsigned short* vb = (unsigned short*)((char*)d_ws + 16384);   // 4 MiB
  unsigned short* wb = vb + 64 * TT * DD;                        // 4 MiB

  const bool pre = ws_size >= (size_t)16384 + 2u * 64 * TT * DD * 2;
  if (pre) {
    hipLaunchKernelGGL(conv_kernel, dim3(2048), dim3(256), 0, stream,
                       video, wifi, vb, wb);
    hipLaunchKernelGGL((pair_kernel<true>), dim3(64 * 64), dim3(512), 0, stream,
                       video, wifi, vb, wb, dense);
  } else {
    hipLaunchKernelGGL((pair_kernel<false>), dim3(64 * 64), dim3(512), 0, stream,
                       video, wifi, vb, wb, dense);
  }
  hipLaunchKernelGGL(loss_kernel, dim3(1), dim3(64), 0, stream,
                     dense, scale, (float*)d_out);
}